// Round 1
// baseline (493.810 us; speedup 1.0000x reference)
//
#include <hip/hip_runtime.h>
#include <hip/hip_bf16.h>
#include <math.h>

// 3-layer GCN on MI355X.
// R5: fused CSR build — atomicAdd returns the slot, so the adjacency write
//     happens in the same kernel (eliminates rank[] round-trip + 2nd random
//     scatter pass). dinv array/kernel eliminated: both consumers already
//     read cnt, rsqrtf(cnt+1) is 1 VALU op vs a 4B load.
// Agg (unchanged from R4): wave per node, lane = bf16x2 feature pair,
//     half-waves process even/odd edges, fp32 accum.

#define FDIM 64

// ---------- fused CSR build ----------

// adjF[col*cap + slot] = row, slot from atomicAdd(&cnt[col],1).
// Slots >= cap are dropped (agg slow-path guard covers deg>cap, prob ~0).
__global__ void build_adj_kernel(const int* __restrict__ row, const int* __restrict__ col,
                                 int* __restrict__ cnt, int* __restrict__ adjF,
                                 int e, int cap) {
    int i = blockIdx.x * blockDim.x + threadIdx.x;
    if (i < e) {
        int c = col[i];
        int r = atomicAdd(&cnt[c], 1);
        if (r < cap) adjF[(size_t)c * cap + r] = row[i];
    }
}

// ---------- per-layer compute ----------

// Hs[n,64] = bf16( rsqrt(cnt+1) * (X[n,64] @ W[64,64]) )
__global__ __launch_bounds__(256) void gemm_kernel(const float* __restrict__ X,
                                                   const float* __restrict__ W,
                                                   const int* __restrict__ cnt,
                                                   __hip_bfloat16* __restrict__ Hout, int n) {
    __shared__ float Ws[64][64];
    __shared__ float Xs[64][64];
    const int t = threadIdx.x;
    const int row0 = blockIdx.x * 64;
    #pragma unroll
    for (int i = t; i < 4096; i += 256) Ws[i >> 6][i & 63] = W[i];
    #pragma unroll
    for (int i = t; i < 4096; i += 256) {
        int r = i >> 6, c = i & 63;
        int gr = row0 + r;
        Xs[r][c] = (gr < n) ? X[(size_t)gr * FDIM + c] : 0.0f;
    }
    __syncthreads();
    const int j = t & 63;
    const int ng = t >> 6;
    float acc[16];
    #pragma unroll
    for (int r = 0; r < 16; r++) acc[r] = 0.0f;
    for (int k = 0; k < 64; k++) {
        float w = Ws[k][j];
        #pragma unroll
        for (int r = 0; r < 16; r++)
            acc[r] += Xs[ng * 16 + r][k] * w;
    }
    #pragma unroll
    for (int r = 0; r < 16; r++) {
        int gr = row0 + ng * 16 + r;
        if (gr < n) {
            float dv = rsqrtf((float)cnt[gr] + 1.0f);   // +1 self loop
            Hout[(size_t)gr * FDIM + j] = __float2bfloat16(acc[r] * dv);
        }
    }
}

// out[v][:] = dinv(v) * ( hs[v][:] + sum_{u in N_in(v)} hs[u][:] ) + b ; optional ELU.
// Wave per node. lane&31 = feature PAIR (bf16x2); lane>>5 = half (even/odd edges).
__global__ __launch_bounds__(256) void agg_kernel(const __hip_bfloat16* __restrict__ hs,
                                                  const int* __restrict__ adjF,
                                                  const int* __restrict__ cnt,
                                                  const float* __restrict__ bias,
                                                  float* __restrict__ out,
                                                  int n, int cap, int do_elu,
                                                  const int* __restrict__ erow,
                                                  const int* __restrict__ ecol, int etot) {
    const int v = blockIdx.x * 4 + (threadIdx.x >> 6);
    const int lane = threadIdx.x & 63;
    if (v >= n) return;
    const int f2 = lane & 31;
    const int half = lane >> 5;
    const int deg = cnt[v];
    const float dv = rsqrtf((float)deg + 1.0f);         // +1 self loop
    const __hip_bfloat162* __restrict__ hs2 = (const __hip_bfloat162*)hs;

    float2 a0 = {0.f,0.f}, a1 = {0.f,0.f}, a2 = {0.f,0.f}, a3 = {0.f,0.f};
    float2 a4 = {0.f,0.f}, a5 = {0.f,0.f}, a6 = {0.f,0.f}, a7 = {0.f,0.f};

    // self loop (add once: half 0 only)
    if (half == 0) {
        __hip_bfloat162 sv = hs2[(size_t)v * 32 + f2];
        a0.x = __bfloat162float(sv.x);
        a0.y = __bfloat162float(sv.y);
    }

    if (deg <= cap) {                       // fast path (always, in practice)
        const int* __restrict__ av = adjF + (size_t)v * cap;
        for (int base = 0; base < deg; base += 64) {
            int m = deg - base; if (m > 64) m = 64;
            int uvec = 0;
            if (lane < m) uvec = av[base + lane];        // coalesced
            const int pairs = m >> 1;
            int k = 0;
            for (; k + 8 <= pairs; k += 8) {
                int u0 = __shfl(uvec, 2*(k+0) + half, 64);
                int u1 = __shfl(uvec, 2*(k+1) + half, 64);
                int u2 = __shfl(uvec, 2*(k+2) + half, 64);
                int u3 = __shfl(uvec, 2*(k+3) + half, 64);
                int u4 = __shfl(uvec, 2*(k+4) + half, 64);
                int u5 = __shfl(uvec, 2*(k+5) + half, 64);
                int u6 = __shfl(uvec, 2*(k+6) + half, 64);
                int u7 = __shfl(uvec, 2*(k+7) + half, 64);
                __hip_bfloat162 b0 = hs2[(size_t)u0 * 32 + f2];
                __hip_bfloat162 b1 = hs2[(size_t)u1 * 32 + f2];
                __hip_bfloat162 b2 = hs2[(size_t)u2 * 32 + f2];
                __hip_bfloat162 b3 = hs2[(size_t)u3 * 32 + f2];
                __hip_bfloat162 b4 = hs2[(size_t)u4 * 32 + f2];
                __hip_bfloat162 b5 = hs2[(size_t)u5 * 32 + f2];
                __hip_bfloat162 b6 = hs2[(size_t)u6 * 32 + f2];
                __hip_bfloat162 b7 = hs2[(size_t)u7 * 32 + f2];
                a0.x += __bfloat162float(b0.x); a0.y += __bfloat162float(b0.y);
                a1.x += __bfloat162float(b1.x); a1.y += __bfloat162float(b1.y);
                a2.x += __bfloat162float(b2.x); a2.y += __bfloat162float(b2.y);
                a3.x += __bfloat162float(b3.x); a3.y += __bfloat162float(b3.y);
                a4.x += __bfloat162float(b4.x); a4.y += __bfloat162float(b4.y);
                a5.x += __bfloat162float(b5.x); a5.y += __bfloat162float(b5.y);
                a6.x += __bfloat162float(b6.x); a6.y += __bfloat162float(b6.y);
                a7.x += __bfloat162float(b7.x); a7.y += __bfloat162float(b7.y);
            }
            for (; k < pairs; k++) {
                int u = __shfl(uvec, 2*k + half, 64);
                __hip_bfloat162 b = hs2[(size_t)u * 32 + f2];
                a0.x += __bfloat162float(b.x); a0.y += __bfloat162float(b.y);
            }
            if (m & 1) {                                  // odd tail edge
                int u = __shfl(uvec, m - 1, 64);
                if (half == 0) {
                    __hip_bfloat162 b = hs2[(size_t)u * 32 + f2];
                    a1.x += __bfloat162float(b.x); a1.y += __bfloat162float(b.y);
                }
            }
        }
    } else {
        // slow path: deg > cap (prob ~0) — wave-cooperative scan of raw edges
        for (int base = 0; base < etot; base += 64) {
            int m = etot - base; if (m > 64) m = 64;
            int c = -1, r = 0;
            if (lane < m) { c = ecol[base + lane]; r = erow[base + lane]; }
            unsigned long long mask = __ballot(c == v);
            while (mask) {
                int j = __ffsll((long long)mask) - 1;
                mask &= mask - 1;
                int u = __shfl(r, j, 64);
                if (half == 0) {
                    __hip_bfloat162 b = hs2[(size_t)u * 32 + f2];
                    a0.x += __bfloat162float(b.x); a0.y += __bfloat162float(b.y);
                }
            }
        }
    }

    float2 tot;
    tot.x = ((a0.x + a1.x) + (a2.x + a3.x)) + ((a4.x + a5.x) + (a6.x + a7.x));
    tot.y = ((a0.y + a1.y) + (a2.y + a3.y)) + ((a4.y + a5.y) + (a6.y + a7.y));
    tot.x += __shfl_xor(tot.x, 32, 64);    // combine halves
    tot.y += __shfl_xor(tot.y, 32, 64);

    if (half == 0) {
        float2 bv = ((const float2*)bias)[f2];
        float rx = tot.x * dv + bv.x;
        float ry = tot.y * dv + bv.y;
        if (do_elu) {
            rx = (rx > 0.0f) ? rx : (__expf(rx) - 1.0f);
            ry = (ry > 0.0f) ? ry : (__expf(ry) - 1.0f);
        }
        ((float2*)out)[(size_t)v * 32 + f2] = make_float2(rx, ry);
    }
}

// ---------- launch ----------

extern "C" void kernel_launch(void* const* d_in, const int* in_sizes, int n_in,
                              void* d_out, int out_size, void* d_ws, size_t ws_size,
                              hipStream_t stream) {
    const float* x   = (const float*)d_in[0];
    const int*   ei  = (const int*)d_in[1];
    const float* W1  = (const float*)d_in[2];
    const float* b1  = (const float*)d_in[3];
    const float* W2  = (const float*)d_in[4];
    const float* b2  = (const float*)d_in[5];
    const float* W3  = (const float*)d_in[6];
    const float* b3  = (const float*)d_in[7];

    const int N = in_sizes[0] / FDIM;      // 100000
    const int E = in_sizes[1] / 2;         // 1600000
    const int* erow = ei;                   // sources
    const int* ecol = ei + E;               // targets

    char* p = (char*)d_ws;
    __hip_bfloat16* hsb = (__hip_bfloat16*)p;  p += (size_t)N * FDIM * sizeof(__hip_bfloat16); // 12.8 MB
    int*   cnt  = (int*)p;   p += (size_t)N * sizeof(int);
    int*   adjF = (int*)p;

    // adjacency capacity: biggest of {64,48,32} that fits the workspace
    size_t used = (size_t)(p - (char*)d_ws);
    int cap = 64;
    while (cap > 32 && used + (size_t)N * cap * sizeof(int) > ws_size) cap -= 16;

    float* outb = (float*)d_out;

    const int TB = 256;
    const int nblkE = (E + TB - 1) / TB;
    const int nblkG = (N + 63) / 64;
    const int nblkA = (N + 3) / 4;

    hipMemsetAsync(cnt, 0, (size_t)N * sizeof(int), stream);
    build_adj_kernel<<<nblkE, TB, 0, stream>>>(erow, ecol, cnt, adjF, E, cap);

    gemm_kernel<<<nblkG, TB, 0, stream>>>(x, W1, cnt, hsb, N);
    agg_kernel<<<nblkA, TB, 0, stream>>>(hsb, adjF, cnt, b1, outb, N, cap, 1, erow, ecol, E);
    gemm_kernel<<<nblkG, TB, 0, stream>>>(outb, W2, cnt, hsb, N);
    agg_kernel<<<nblkA, TB, 0, stream>>>(hsb, adjF, cnt, b2, outb, N, cap, 1, erow, ecol, E);
    gemm_kernel<<<nblkG, TB, 0, stream>>>(outb, W3, cnt, hsb, N);
    agg_kernel<<<nblkA, TB, 0, stream>>>(hsb, adjF, cnt, b3, outb, N, cap, 0, erow, ecol, E);
}